// Round 3
// baseline (868.863 us; speedup 1.0000x reference)
//
#include <hip/hip_runtime.h>

// Problem constants
#define L_DIM 8192
#define V_DIM 25
#define C_DIM 256
#define P_DIM 3
#define KSZ 9
#define TILE_T 120          // output t's per block
#define SLOTS 128           // TILE_T + 8 halo
#define SS_STRIDE 27        // odd stride -> conflict-free, room for half1 pad col
#define CH_FLOATS (L_DIM * V_DIM)   // 204800 floats per (p,c) channel
#define NGROUPS (P_DIM * SLOTS * V_DIM / 4)   // 2400 float4 groups per block
#define G_PER_P (SLOTS * V_DIM / 4)           // 800

typedef const __attribute__((address_space(1))) unsigned int* gptr_t;
typedef __attribute__((address_space(3))) unsigned int* lptr_t;

// Pack A (3x25x25) into Apad rows of 32 floats, 16B aligned:
//   slots 0..12  = A[pv][0..12]   (half 0)
//   slots 16..27 = A[pv][13..24]  (half 1), slot 28..31 = 0 (harmless pad FMA)
__global__ void prep_A(const float* __restrict__ A, float* __restrict__ Apad) {
    int idx = blockIdx.x * blockDim.x + threadIdx.x;
    if (idx < P_DIM * V_DIM * 32) {
        int slot = idx & 31;
        int pv = idx >> 5;
        float v = 0.f;
        if (slot < 13) v = A[pv * 25 + slot];
        else if (slot >= 16 && slot < 28) v = A[pv * 25 + (slot - 3)];
        Apad[idx] = v;
    }
}

__global__ __launch_bounds__(256, 3) void stgcn_kernel(
    const float* __restrict__ x, const float* __restrict__ Apad,
    float* __restrict__ out)
{
    __shared__ __align__(16) float xs[P_DIM][SLOTS][V_DIM];  // 38400 B
    __shared__ __align__(16) float ss[SLOTS][SS_STRIDE];     // 13824 B

    const int tid = threadIdx.x;
    const int tile = blockIdx.x;
    const int c = blockIdx.y;
    const int t0 = tile * TILE_T;
    const int base_t = t0 - (KSZ - 1);          // first staged t (may be <0)

    // ---- Stage x window [base_t, base_t+128) for 3 p's ----
    // Window per p = contiguous floats [base_t*25, base_t*25+3200) of channel
    // (p*C+c). base_t*25 = 3000*tile - 200 == 0 (mod 4) and the valid-range
    // cut points (0, 204800) are mod-4 aligned, so each float4 group is
    // entirely valid or entirely OOB.
    //
    // global_load_lds writes LDS at wave-uniform base + lane*16 and is only
    // safe under a FULL exec mask (m104/m173). So: per wave, if ALL 64 lanes
    // are valid -> fire-and-forget global_load_lds (no VGPR round-trip, loads
    // issue back-to-back, one vmcnt drain at the barrier). Any mixed wave
    // (it=9 upper half; tile 0/68 halo) -> predicated float4 + ds_write_b128.
    {
        float* xsf = &xs[0][0][0];
        const int o0 = base_t * V_DIM;          // first float offset in channel
        #pragma unroll
        for (int it = 0; it < 10; ++it) {
            int g = it * 256 + tid;
            bool inrange = (g < NGROUPS);
            int p = g / G_PER_P;                // 0..2 for inrange lanes
            int o = o0 + 4 * (g - p * G_PER_P); // float offset in channel
            bool valid = inrange && (o >= 0) && (o < CH_FLOATS);
            unsigned long long m = __ballot(valid);
            if (m == ~0ull) {                   // wave-uniform fast path
                const float* src = x + (size_t)(p * C_DIM + c) * CH_FLOATS + o;
                __builtin_amdgcn_global_load_lds(
                    (gptr_t)src, (lptr_t)(xsf + (size_t)g * 4), 16, 0, 0);
            } else if (inrange) {               // boundary/tail wave, rare
                float4 val = make_float4(0.f, 0.f, 0.f, 0.f);
                if (valid)
                    val = *reinterpret_cast<const float4*>(
                        x + (size_t)(p * C_DIM + c) * CH_FLOATS + o);
                *reinterpret_cast<float4*>(xsf + (size_t)g * 4) = val;
            }
        }
    }
    __syncthreads();   // drains vmcnt+lgkmcnt: all staged data visible

    // ---- Pass 1: s[t][w] = sum_{p,v} x[p][t][v] * A[p][v][w] ----
    // half is wave-uniform (waves 0,1 -> 0; waves 2,3 -> 1); readfirstlane so
    // the compiler proves A addresses uniform -> scalar (s_load) K$ loads.
    const int half = __builtin_amdgcn_readfirstlane(tid >> 7);
    const int tl = tid & (SLOTS - 1);
    const float* Ab = Apad + half * 16;

    float acc[13];
    #pragma unroll
    for (int i = 0; i < 13; i++) acc[i] = 0.f;

    #pragma unroll
    for (int p = 0; p < P_DIM; p++) {
        const float* xrow = &xs[p][tl][0];
        #pragma unroll 5
        for (int v = 0; v < V_DIM; v++) {
            float xv = xrow[v];
            const float* a = Ab + (p * V_DIM + v) * 32;
            #pragma unroll
            for (int w = 0; w < 13; w++)
                acc[w] = fmaf(xv, a[w], acc[w]);   // a[w] in SGPR
        }
    }

    {   // half0 -> cols 0..12, half1 -> cols 13..25 (col 25 is pad, never read)
        float* srow = &ss[tl][half * 13];
        #pragma unroll
        for (int w = 0; w < 13; w++) srow[w] = acc[w];
    }
    __syncthreads();

    // ---- Pass 2: causal 9-tap sliding sum along t, running-window form ----
    if (tid < 250) {
        int w = tid % 25;
        int strip = tid / 25;                    // 10 strips x 12 t's = 120
        int slot0 = strip * 12 + (KSZ - 1);      // slot of first output t
        float sum = 0.f;
        #pragma unroll
        for (int j = 0; j < KSZ; j++) sum += ss[slot0 - (KSZ - 1) + j][w];

        int t = t0 + strip * 12;
        size_t obase = (size_t)c * (L_DIM * V_DIM);
        if (t < L_DIM) out[obase + (size_t)t * V_DIM + w] = sum;
        #pragma unroll
        for (int k = 1; k < 12; k++) {
            sum += ss[slot0 + k][w] - ss[slot0 + k - KSZ][w];
            int tk = t + k;
            if (tk < L_DIM) out[obase + (size_t)tk * V_DIM + w] = sum;
        }
    }
}

extern "C" void kernel_launch(void* const* d_in, const int* in_sizes, int n_in,
                              void* d_out, int out_size, void* d_ws, size_t ws_size,
                              hipStream_t stream) {
    const float* x = (const float*)d_in[0];
    const float* A = (const float*)d_in[1];
    float* outp = (float*)d_out;
    float* Apad = (float*)d_ws;                  // 3*25*32*4 = 9600 B of ws

    hipLaunchKernelGGL(prep_A, dim3(10), dim3(256), 0, stream, A, Apad);

    dim3 grid((L_DIM + TILE_T - 1) / TILE_T, C_DIM);   // (69, 256)
    hipLaunchKernelGGL(stgcn_kernel, grid, dim3(256), 0, stream, x, Apad, outp);
}

// Round 4
// 860.802 us; speedup vs baseline: 1.0094x; 1.0094x over previous
//
#include <hip/hip_runtime.h>

// Problem constants
#define L_DIM 8192
#define V_DIM 25
#define C_DIM 256
#define P_DIM 3
#define KSZ 9
#define TILE_T 56           // output t's per block
#define SLOTS 64            // TILE_T + 8 halo
#define SS_STRIDE 29        // odd stride -> conflict-free; 28 cols used (4x7)
#define CH_FLOATS (L_DIM * V_DIM)   // 204800 floats per (p,c) channel
#define NGROUPS (P_DIM * SLOTS * V_DIM / 4)   // 1200 float4 groups per block
#define G_PER_P (SLOTS * V_DIM / 4)           // 400

typedef const __attribute__((address_space(1))) unsigned int* gptr_t;
typedef __attribute__((address_space(3))) unsigned int* lptr_t;

// Pack A (3x25x25) into Apad rows of 32 floats, 16B aligned, 4 quarters of 7:
//   slot q*8+j = A[pv][q*7+j] for j<7 and q*7+j<25, else 0 (harmless pad FMA).
__global__ void prep_A(const float* __restrict__ A, float* __restrict__ Apad) {
    int idx = blockIdx.x * blockDim.x + threadIdx.x;
    if (idx < P_DIM * V_DIM * 32) {
        int slot = idx & 31;
        int pv = idx >> 5;
        int q = slot >> 3, j = slot & 7;
        int col = q * 7 + j;
        float v = 0.f;
        if (j < 7 && col < 25) v = A[pv * 25 + col];
        Apad[idx] = v;
    }
}

__global__ __launch_bounds__(256, 6) void stgcn_kernel(
    const float* __restrict__ x, const float* __restrict__ Apad,
    float* __restrict__ out)
{
    __shared__ __align__(16) float xs[P_DIM][SLOTS][V_DIM];  // 19200 B
    __shared__ __align__(16) float ss[SLOTS][SS_STRIDE];     //  7424 B
    // total 26624 B -> 6 blocks/CU (24 waves, 75% occ) vs 3 at SLOTS=128

    const int tid = threadIdx.x;
    const int tile = blockIdx.x;
    const int c = blockIdx.y;
    const int t0 = tile * TILE_T;
    const int base_t = t0 - (KSZ - 1);          // first staged t (may be <0)

    // ---- Stage x window [base_t, base_t+64) for 3 p's ----
    // Window per p = contiguous floats [base_t*25, base_t*25+1600) of channel
    // (p*C+c). base_t*25 = 1400*tile - 200 == 0 (mod 4) and the valid-range
    // cut points (0, 204800) are mod-4 aligned, so each float4 group is
    // entirely valid or entirely OOB.
    //
    // global_load_lds writes LDS at wave-uniform base + lane*16 and is only
    // safe under a FULL exec mask. Per wave: all 64 lanes valid ->
    // fire-and-forget global_load_lds (no VGPR round-trip, one vmcnt drain at
    // the barrier). Mixed wave (tail of it=4; tile 0/146 halo) -> predicated
    // float4 + ds_write_b128.
    {
        float* xsf = &xs[0][0][0];
        const int o0 = base_t * V_DIM;          // first float offset in channel
        #pragma unroll
        for (int it = 0; it < 5; ++it) {
            int g = it * 256 + tid;
            bool inrange = (g < NGROUPS);
            int p = g / G_PER_P;                // 0..2 for inrange lanes
            int o = o0 + 4 * (g - p * G_PER_P); // float offset in channel
            bool valid = inrange && (o >= 0) && (o < CH_FLOATS);
            unsigned long long m = __ballot(valid);
            if (m == ~0ull) {                   // wave-uniform fast path
                const float* src = x + (size_t)(p * C_DIM + c) * CH_FLOATS + o;
                __builtin_amdgcn_global_load_lds(
                    (gptr_t)src, (lptr_t)(xsf + (size_t)g * 4), 16, 0, 0);
            } else if (inrange) {               // boundary/tail wave, rare
                float4 val = make_float4(0.f, 0.f, 0.f, 0.f);
                if (valid)
                    val = *reinterpret_cast<const float4*>(
                        x + (size_t)(p * C_DIM + c) * CH_FLOATS + o);
                *reinterpret_cast<float4*>(xsf + (size_t)g * 4) = val;
            }
        }
    }
    __syncthreads();   // drains vmcnt+lgkmcnt: all staged data visible

    // ---- Pass 1: s[t][w] = sum_{p,v} x[p][t][v] * A[p][v][w] ----
    // quarter q is wave-uniform (wave i -> quarter i); readfirstlane so the
    // compiler proves A addresses uniform -> scalar (s_load) K$ loads.
    const int q = __builtin_amdgcn_readfirstlane(tid >> 6);
    const int tl = tid & (SLOTS - 1);
    const float* Ab = Apad + q * 8;

    float acc[7];
    #pragma unroll
    for (int i = 0; i < 7; i++) acc[i] = 0.f;

    #pragma unroll
    for (int p = 0; p < P_DIM; p++) {
        const float* xrow = &xs[p][tl][0];
        #pragma unroll 5
        for (int v = 0; v < V_DIM; v++) {
            float xv = xrow[v];
            const float* a = Ab + (p * V_DIM + v) * 32;
            #pragma unroll
            for (int w = 0; w < 7; w++)
                acc[w] = fmaf(xv, a[w], acc[w]);   // a[w] in SGPR
        }
    }

    {   // quarter q -> cols q*7 .. q*7+6 (cols 25..27 are pad, never read)
        float* srow = &ss[tl][q * 7];
        #pragma unroll
        for (int w = 0; w < 7; w++) srow[w] = acc[w];
    }
    __syncthreads();

    // ---- Pass 2: causal 9-tap sliding sum along t, running-window form ----
    if (tid < 175) {
        int w = tid % 25;
        int strip = tid / 25;                    // 7 strips x 8 t's = 56
        int slot0 = strip * 8 + (KSZ - 1);       // slot of first output t
        float sum = 0.f;
        #pragma unroll
        for (int j = 0; j < KSZ; j++) sum += ss[slot0 - (KSZ - 1) + j][w];

        int t = t0 + strip * 8;
        size_t obase = (size_t)c * (L_DIM * V_DIM);
        if (t < L_DIM) out[obase + (size_t)t * V_DIM + w] = sum;
        #pragma unroll
        for (int k = 1; k < 8; k++) {
            sum += ss[slot0 + k][w] - ss[slot0 + k - KSZ][w];
            int tk = t + k;
            if (tk < L_DIM) out[obase + (size_t)tk * V_DIM + w] = sum;
        }
    }
}

extern "C" void kernel_launch(void* const* d_in, const int* in_sizes, int n_in,
                              void* d_out, int out_size, void* d_ws, size_t ws_size,
                              hipStream_t stream) {
    const float* x = (const float*)d_in[0];
    const float* A = (const float*)d_in[1];
    float* outp = (float*)d_out;
    float* Apad = (float*)d_ws;                  // 3*25*32*4 = 9600 B of ws

    hipLaunchKernelGGL(prep_A, dim3(10), dim3(256), 0, stream, A, Apad);

    dim3 grid((L_DIM + TILE_T - 1) / TILE_T, C_DIM);   // (147, 256)
    hipLaunchKernelGGL(stgcn_kernel, grid, dim3(256), 0, stream, x, Apad, outp);
}